// Round 1
// 632.708 us; speedup vs baseline: 1.0486x; 1.0486x over previous
//
#include <hip/hip_runtime.h>
#include <math.h>

#define BSZ 16
#define DIMM 4096
#define NKVH 8
#define HD 128
#define SEQ 4096
#define NSPLIT 16
#define SPLITLEN 256
#define RPAD 65

// ---------------------------------------------------------------------------
// Async global->LDS stage: 16 B/lane, LDS dst = wave-uniform base + lane*16.
// ---------------------------------------------------------------------------
__device__ __forceinline__ void gll16(const float* src, float* dst) {
  __builtin_amdgcn_global_load_lds(
      (const __attribute__((address_space(1))) void*)src,
      (__attribute__((address_space(3))) void*)dst, 16, 0, 0);
}

// Stage one 16 KB x-chunk (16 batches x 256 dims) into LDS buffer `buf`.
// Wave-uniform LDS base (buf + u*1024 + wave*256); HW adds lane*16.
// Source per lane: x[b = u*4+wave][c*256 + lane*4 .. +3] (contiguous, coalesced).
__device__ __forceinline__ void stage_chunk(const float* __restrict__ xg,
                                            float* __restrict__ buf, int c,
                                            int wave, int lane) {
#pragma unroll
  for (int u = 0; u < 4; ++u) {
    gll16(xg + (size_t)(u * 4 + wave) * DIMM + c * 256 + (lane << 2),
          buf + u * 1024 + wave * 256);
  }
}

// ---------------------------------------------------------------------------
// Skinny GEMV: out[row][b] = sum_d W[row][d] * x[b][d], 16 batches.
// 4 waves/block, 4 rows/wave (16 rows/block). Double-buffered async x staging
// (1 barrier per chunk), W prefetched one chunk ahead in registers.
// res[r] valid for batch b = lane>>2 in each 4-lane group.
// ---------------------------------------------------------------------------
__device__ __forceinline__ void gemv_rows4(const float* __restrict__ xg,
                                           const float* __restrict__ W,
                                           int rbase,
                                           float* __restrict__ x_lds,  // [2*4096]
                                           float* __restrict__ rbuf,
                                           float res[4], int tid) {
  const int lane = tid & 63;
  const int wave = tid >> 6;
  float acc[4][16];
#pragma unroll
  for (int r = 0; r < 4; ++r)
#pragma unroll
    for (int b = 0; b < 16; ++b) acc[r][b] = 0.f;

  // Prologue: stage chunk 0, prefetch W chunk 0.
  stage_chunk(xg, x_lds, 0, wave, lane);
  float4 w4[4];
#pragma unroll
  for (int r = 0; r < 4; ++r)
    w4[r] = *(const float4*)(W + (size_t)(rbase + r) * DIMM + (lane << 2));

  for (int c = 0; c < 16; ++c) {
    // Barrier: chunk c fully staged (compiler drains vmcnt before s_barrier),
    // and all waves done reading buf[(c+1)&1] from iter c-1 -> safe to restage.
    __syncthreads();
    float4 wn[4];
    if (c < 15) {
      stage_chunk(xg, x_lds + ((c + 1) & 1) * 4096, c + 1, wave, lane);
#pragma unroll
      for (int r = 0; r < 4; ++r)
        wn[r] = *(const float4*)(W + (size_t)(rbase + r) * DIMM +
                                 (c + 1) * 256 + (lane << 2));
    }
    const float4* xb = (const float4*)(x_lds + (c & 1) * 4096);
#pragma unroll
    for (int b = 0; b < 16; ++b) {
      float4 xv = xb[b * 64 + lane];
#pragma unroll
      for (int r = 0; r < 4; ++r) {
        acc[r][b] = fmaf(w4[r].x, xv.x, acc[r][b]);
        acc[r][b] = fmaf(w4[r].y, xv.y, acc[r][b]);
        acc[r][b] = fmaf(w4[r].z, xv.z, acc[r][b]);
        acc[r][b] = fmaf(w4[r].w, xv.w, acc[r][b]);
      }
    }
    if (c < 15) {
#pragma unroll
      for (int r = 0; r < 4; ++r) w4[r] = wn[r];
    }
  }

  // Cross-lane reduction via per-wave LDS transpose (rbuf is wave-private).
#pragma unroll
  for (int r = 0; r < 4; ++r) {
    __syncthreads();
#pragma unroll
    for (int b = 0; b < 16; ++b) rbuf[b * RPAD + lane] = acc[r][b];
    __syncthreads();
    int bb = lane >> 2, j = lane & 3;
    float s = 0.f;
#pragma unroll
    for (int k = 0; k < 16; ++k) s += rbuf[bb * RPAD + j * 16 + k];
    s += __shfl_xor(s, 1);
    s += __shfl_xor(s, 2);
    res[r] = s;
  }
}

// ---------------------------------------------------------------------------
// Kernel 1: QKV projection + RoPE. NO input mutation: new k/v rows go to
// workspace (k_ws/v_ws), not the cache. rows 0..4095 = wq, 4096..5119 = wk,
// 5120..6143 = wv. 16 rows/block, grid 384.
// ---------------------------------------------------------------------------
__global__ __launch_bounds__(256) void qkv_kernel(
    const float* __restrict__ x, const float* __restrict__ wq,
    const float* __restrict__ wk, const float* __restrict__ wv,
    const float* __restrict__ fcos, const float* __restrict__ fsin,
    float* __restrict__ q_ws, float* __restrict__ k_ws,
    float* __restrict__ v_ws) {
  __shared__ float x_lds[2 * 4096];
  __shared__ float red[4][16 * RPAD];
  const int tid = threadIdx.x;
  const int lane = tid & 63;
  const int wave = tid >> 6;
  const int row0 = blockIdx.x * 16 + wave * 4;

  const float* W;
  int rbase, kind;  // 0=q, 1=k, 2=v
  if (row0 < 4096)      { W = wq; rbase = row0;        kind = 0; }
  else if (row0 < 5120) { W = wk; rbase = row0 - 4096; kind = 1; }
  else                  { W = wv; rbase = row0 - 5120; kind = 2; }

  float res[4];
  gemv_rows4(x, W, rbase, x_lds, red[wave], res, tid);

  if (kind <= 1) {  // RoPE on pairs (0,1) and (2,3); rbase % 4 == 0
#pragma unroll
    for (int pr = 0; pr < 2; ++pr) {
      int i = ((rbase + pr * 2) & 127) >> 1;
      float c = fcos[i], s = fsin[i];
      float a = res[pr * 2], b2 = res[pr * 2 + 1];
      res[pr * 2]     = a * c - b2 * s;
      res[pr * 2 + 1] = a * s + b2 * c;
    }
  }
  if ((lane & 3) == 0) {
    int b = lane >> 2;
    if (kind == 0) {
#pragma unroll
      for (int r = 0; r < 4; ++r) q_ws[(size_t)b * 4096 + rbase + r] = res[r];
    } else {
      int kvh = rbase >> 7, dpos = rbase & 127;
      float* dst = (kind == 1) ? k_ws : v_ws;
#pragma unroll
      for (int r = 0; r < 4; ++r)
        dst[((size_t)b * NKVH + kvh) * HD + dpos + r] = res[r];
    }
  }
}

// ---------------------------------------------------------------------------
// Kernel 2: flash-decode attention partials. Positions 0..4094 come from the
// (unmodified) caches; position 4095 comes from k_ws/v_ws (fresh QKV output).
// grid (NSPLIT, NKVH, BSZ); block 256. 4 GQA q-heads, 256 keys per block.
// ---------------------------------------------------------------------------
__global__ __launch_bounds__(256) void attn_kernel(
    const float* __restrict__ ck, const float* __restrict__ cv,
    const float* __restrict__ q_ws, const float* __restrict__ k_ws,
    const float* __restrict__ v_ws, float* __restrict__ ml_ws,
    float* __restrict__ opart) {
  __shared__ float sc[SPLITLEN * 4];   // [p][h]
  __shared__ float part[32 * 128];     // [half*16 + wave*4 + h][d]
  const int tid = threadIdx.x, lane = tid & 63, wave = tid >> 6;
  const int split = blockIdx.x, kvh = blockIdx.y, b = blockIdx.z;
  const int p0 = split * SPLITLEN;
  const float scale = 0.08838834764831845f;  // 1/sqrt(128)

  // ---- Phase 1: scores = q . k  (8 lanes per row, shuffle reduce) ----
  {
    const int dsub = (lane & 7) << 2;
    const int prow = lane >> 3;
    float4 q4[4][4];
#pragma unroll
    for (int h = 0; h < 4; ++h)
#pragma unroll
      for (int j = 0; j < 4; ++j) {
        float4 t = *(const float4*)(q_ws + (size_t)b * 4096 + (kvh * 4 + h) * 128 + j * 32 + dsub);
        q4[h][j] = make_float4(t.x * scale, t.y * scale, t.z * scale, t.w * scale);
      }
#pragma unroll 2
    for (int it = 0; it < 8; ++it) {
      int pl = wave * 64 + it * 8 + prow;
      const float* kp = (p0 + pl == SEQ - 1)
                            ? (k_ws + ((size_t)b * NKVH + kvh) * HD)
                            : (ck + ((size_t)(b * 4096 + p0 + pl) * 8 + kvh) * 128);
      float s0 = 0, s1 = 0, s2 = 0, s3 = 0;
#pragma unroll
      for (int j = 0; j < 4; ++j) {
        float4 k4 = *(const float4*)(kp + j * 32 + dsub);
        s0 = fmaf(k4.x, q4[0][j].x, s0); s0 = fmaf(k4.y, q4[0][j].y, s0);
        s0 = fmaf(k4.z, q4[0][j].z, s0); s0 = fmaf(k4.w, q4[0][j].w, s0);
        s1 = fmaf(k4.x, q4[1][j].x, s1); s1 = fmaf(k4.y, q4[1][j].y, s1);
        s1 = fmaf(k4.z, q4[1][j].z, s1); s1 = fmaf(k4.w, q4[1][j].w, s1);
        s2 = fmaf(k4.x, q4[2][j].x, s2); s2 = fmaf(k4.y, q4[2][j].y, s2);
        s2 = fmaf(k4.z, q4[2][j].z, s2); s2 = fmaf(k4.w, q4[2][j].w, s2);
        s3 = fmaf(k4.x, q4[3][j].x, s3); s3 = fmaf(k4.y, q4[3][j].y, s3);
        s3 = fmaf(k4.z, q4[3][j].z, s3); s3 = fmaf(k4.w, q4[3][j].w, s3);
      }
#pragma unroll
      for (int m = 1; m <= 4; m <<= 1) {
        s0 += __shfl_xor(s0, m); s1 += __shfl_xor(s1, m);
        s2 += __shfl_xor(s2, m); s3 += __shfl_xor(s3, m);
      }
      if ((lane & 7) == 0)
        ((float4*)sc)[pl] = make_float4(s0, s1, s2, s3);
    }
  }
  __syncthreads();

  // ---- Phase 1.5: per-split softmax (wave w handles head w) ----
  {
    int h = wave;
    float vals[4];
    float m = -1e30f;
#pragma unroll
    for (int k = 0; k < 4; ++k) {
      vals[k] = sc[(k * 64 + lane) * 4 + h];
      m = fmaxf(m, vals[k]);
    }
#pragma unroll
    for (int mk = 1; mk <= 32; mk <<= 1) m = fmaxf(m, __shfl_xor(m, mk));
    float lsum = 0;
#pragma unroll
    for (int k = 0; k < 4; ++k) {
      float e = __expf(vals[k] - m);
      sc[(k * 64 + lane) * 4 + h] = e;
      lsum += e;
    }
#pragma unroll
    for (int mk = 1; mk <= 32; mk <<= 1) lsum += __shfl_xor(lsum, mk);
    if (lane == 0) {
      int hg = kvh * 4 + h;
      ml_ws[((size_t)(b * 32 + hg) * NSPLIT + split) * 2 + 0] = m;
      ml_ws[((size_t)(b * 32 + hg) * NSPLIT + split) * 2 + 1] = lsum;
    }
  }
  __syncthreads();

  // ---- Phase 2: PV. 2 rows/iter (half-wave each), float4 loads ----
  {
    const int dq = lane & 31;     // float4 column index: d = dq*4
    const int half = lane >> 5;
    float4 a0 = {0,0,0,0}, a1 = {0,0,0,0}, a2 = {0,0,0,0}, a3 = {0,0,0,0};
#pragma unroll 4
    for (int it = 0; it < 32; ++it) {
      int pl = wave * 64 + it * 2 + half;
      const float* vp = (p0 + pl == SEQ - 1)
                            ? (v_ws + ((size_t)b * NKVH + kvh) * HD)
                            : (cv + ((size_t)(b * 4096 + p0 + pl) * 8 + kvh) * 128);
      float4 v4 = *(const float4*)(vp + dq * 4);
      float4 s4 = ((const float4*)sc)[pl];  // 2-way LDS broadcast
      a0.x = fmaf(s4.x, v4.x, a0.x); a0.y = fmaf(s4.x, v4.y, a0.y);
      a0.z = fmaf(s4.x, v4.z, a0.z); a0.w = fmaf(s4.x, v4.w, a0.w);
      a1.x = fmaf(s4.y, v4.x, a1.x); a1.y = fmaf(s4.y, v4.y, a1.y);
      a1.z = fmaf(s4.y, v4.z, a1.z); a1.w = fmaf(s4.y, v4.w, a1.w);
      a2.x = fmaf(s4.z, v4.x, a2.x); a2.y = fmaf(s4.z, v4.y, a2.y);
      a2.z = fmaf(s4.z, v4.z, a2.z); a2.w = fmaf(s4.z, v4.w, a2.w);
      a3.x = fmaf(s4.w, v4.x, a3.x); a3.y = fmaf(s4.w, v4.y, a3.y);
      a3.z = fmaf(s4.w, v4.z, a3.z); a3.w = fmaf(s4.w, v4.w, a3.w);
    }
    int rb = (half * 16 + wave * 4) * 128 + dq * 4;
    *(float4*)&part[rb + 0 * 128] = a0;
    *(float4*)&part[rb + 1 * 128] = a1;
    *(float4*)&part[rb + 2 * 128] = a2;
    *(float4*)&part[rb + 3 * 128] = a3;
  }
  __syncthreads();
  {
    int hh = tid >> 6, dd = (tid & 63) * 2;
    float o0 = 0, o1 = 0;
#pragma unroll
    for (int g = 0; g < 8; ++g) {
      int row = (g >> 2) * 16 + (g & 3) * 4 + hh;
      float2 p2 = *(const float2*)&part[row * 128 + dd];
      o0 += p2.x; o1 += p2.y;
    }
    int hg = kvh * 4 + hh;
    size_t base = ((size_t)(b * 32 + hg) * NSPLIT + split) * 128;
    *(float2*)(opart + base + dd) = make_float2(o0, o1);
  }
}

// ---------------------------------------------------------------------------
// Kernel 3: combine split partials (flash rescale).
// ---------------------------------------------------------------------------
__global__ __launch_bounds__(128) void combine_kernel(
    const float* __restrict__ ml_ws, const float* __restrict__ opart,
    float* __restrict__ attn_ws) {
  int bh = blockIdx.x;  // b*32 + h
  int d = threadIdx.x;
  float mv[NSPLIT], lv[NSPLIT];
  float M = -1e30f;
#pragma unroll
  for (int i = 0; i < NSPLIT; ++i) {
    mv[i] = ml_ws[((size_t)bh * NSPLIT + i) * 2];
    lv[i] = ml_ws[((size_t)bh * NSPLIT + i) * 2 + 1];
    M = fmaxf(M, mv[i]);
  }
  float L = 0, o = 0;
#pragma unroll
  for (int i = 0; i < NSPLIT; ++i) {
    float w = __expf(mv[i] - M);
    L += w * lv[i];
    o += w * opart[((size_t)bh * NSPLIT + i) * 128 + d];
  }
  attn_ws[(size_t)bh * 128 + d] = o / L;
}

// ---------------------------------------------------------------------------
// Kernel 4: output projection with wo. 16 rows/block, grid 256.
// ---------------------------------------------------------------------------
__global__ __launch_bounds__(256) void oproj_kernel(
    const float* __restrict__ xin, const float* __restrict__ wo,
    float* __restrict__ out) {
  __shared__ float x_lds[2 * 4096];
  __shared__ float red[4][16 * RPAD];
  const int tid = threadIdx.x;
  const int lane = tid & 63;
  const int wave = tid >> 6;
  const int row0 = blockIdx.x * 16 + wave * 4;
  float res[4];
  gemv_rows4(xin, wo, row0, x_lds, red[wave], res, tid);
  if ((lane & 3) == 0) {
    int b = lane >> 2;
#pragma unroll
    for (int r = 0; r < 4; ++r) out[(size_t)b * 4096 + row0 + r] = res[r];
  }
}

extern "C" void kernel_launch(void* const* d_in, const int* in_sizes, int n_in,
                              void* d_out, int out_size, void* d_ws, size_t ws_size,
                              hipStream_t stream) {
  const float* x  = (const float*)d_in[0];
  const float* wq = (const float*)d_in[1];
  const float* wk = (const float*)d_in[2];
  const float* wv = (const float*)d_in[3];
  const float* wo = (const float*)d_in[4];
  const float* ck = (const float*)d_in[5];  // NOT mutated (new row lives in ws)
  const float* cv = (const float*)d_in[6];
  const float* fc = (const float*)d_in[7];
  const float* fs = (const float*)d_in[8];

  float* ws      = (float*)d_ws;
  float* q_ws    = ws;               // 16*4096            = 65536
  float* k_ws    = q_ws + 65536;     // 16*8*128           = 16384
  float* v_ws    = k_ws + 16384;     // 16*8*128           = 16384
  float* ml_ws   = v_ws + 16384;     // 16*32*16*2         = 16384
  float* opart   = ml_ws + 16384;    // 16*32*16*128       = 1048576
  float* attn_ws = opart + 1048576;  // 16*4096            = 65536
  // total ~4.9 MB of workspace

  qkv_kernel<<<384, 256, 0, stream>>>(x, wq, wk, wv, fc, fs, q_ws, k_ws, v_ws);
  attn_kernel<<<dim3(NSPLIT, NKVH, BSZ), 256, 0, stream>>>(ck, cv, q_ws, k_ws, v_ws,
                                                           ml_ws, opart);
  combine_kernel<<<BSZ * 32, 128, 0, stream>>>(ml_ws, opart, attn_ws);
  oproj_kernel<<<256, 256, 0, stream>>>(attn_ws, wo, (float*)d_out);
}

// Round 2
// 615.224 us; speedup vs baseline: 1.0784x; 1.0284x over previous
//
#include <hip/hip_runtime.h>
#include <math.h>

#define BSZ 16
#define DIMM 4096
#define NKVH 8
#define HD 128
#define SEQ 4096
#define NSPLIT 32
#define SPLITLEN 128
#define RPAD 65

typedef float v4f __attribute__((ext_vector_type(4)));

__device__ __forceinline__ v4f ldg4(const float* p) { return *(const v4f*)p; }
// Nontemporal: single-use streams (W rows, K/V cache) — don't evict x / q from L1/L2.
__device__ __forceinline__ v4f ldnt4(const float* p) {
  return __builtin_nontemporal_load((const v4f*)p);
}

// ---------------------------------------------------------------------------
// Barrier-free skinny GEMV: out[row][b] = sum_d W[row][d] * x[b][d], 16 batches.
// 4 waves/block, 4 rows/wave. No LDS staging: x (256 KB total) is L2/L3-resident,
// each lane loads its x slice directly (L1-hit across the 4 waves); W rows are
// streamed nontemporal from HBM with a one-chunk register prefetch. ZERO
// __syncthreads in the main loop -> no vmcnt(0) drains, waves free-run.
// res[r] valid for batch b = lane>>2 in each 4-lane group.
// ---------------------------------------------------------------------------
__device__ __forceinline__ void gemv4_direct(const float* __restrict__ xg,
                                             const float* __restrict__ W,
                                             int rbase,
                                             float* __restrict__ rbuf,  // wave-private [16*RPAD]
                                             float res[4], int lane) {
  float acc[4][16];
#pragma unroll
  for (int r = 0; r < 4; ++r)
#pragma unroll
    for (int b = 0; b < 16; ++b) acc[r][b] = 0.f;

  const float* wbase = W + (size_t)rbase * DIMM + (lane << 2);
  const float* xbase = xg + (lane << 2);

  // Prefetch W chunk 0.
  v4f w4[4];
#pragma unroll
  for (int r = 0; r < 4; ++r) w4[r] = ldnt4(wbase + (size_t)r * DIMM);

  for (int c = 0; c < 16; ++c) {
    // Prefetch next W chunk (HBM, ~900 cyc) while computing this one.
    v4f wn[4];
    if (c < 15) {
#pragma unroll
      for (int r = 0; r < 4; ++r)
        wn[r] = ldnt4(wbase + (size_t)r * DIMM + (c + 1) * 256);
    }
    // x loads hit L1/L2 (x fully cache-resident); consume in two half-batches
    // to bound live VGPRs (acc 64 + w 32 + xv 32 ~ 150).
#pragma unroll
    for (int bh = 0; bh < 2; ++bh) {
      v4f xv[8];
#pragma unroll
      for (int b = 0; b < 8; ++b)
        xv[b] = ldg4(xbase + (size_t)(bh * 8 + b) * DIMM + c * 256);
#pragma unroll
      for (int b = 0; b < 8; ++b)
#pragma unroll
        for (int r = 0; r < 4; ++r)
#pragma unroll
          for (int e = 0; e < 4; ++e)
            acc[r][bh * 8 + b] = fmaf(w4[r][e], xv[b][e], acc[r][bh * 8 + b]);
    }
    if (c < 15) {
#pragma unroll
      for (int r = 0; r < 4; ++r) w4[r] = wn[r];
    }
  }

  // Cross-lane reduction via wave-private LDS transpose. No barriers needed:
  // DS ops from one wave complete in order (lgkmcnt), rbuf is wave-private.
#pragma unroll
  for (int r = 0; r < 4; ++r) {
#pragma unroll
    for (int b = 0; b < 16; ++b) rbuf[b * RPAD + lane] = acc[r][b];
    int bb = lane >> 2, j = lane & 3;
    float s = 0.f;
#pragma unroll
    for (int k = 0; k < 16; ++k) s += rbuf[bb * RPAD + j * 16 + k];
    s += __shfl_xor(s, 1);
    s += __shfl_xor(s, 2);
    res[r] = s;
  }
}

// ---------------------------------------------------------------------------
// Kernel 1: QKV projection + RoPE. No input mutation: new k/v rows go to
// workspace. rows 0..4095 = wq, 4096..5119 = wk, 5120..6143 = wv.
// 16 rows/block, grid 384.
// ---------------------------------------------------------------------------
__global__ __launch_bounds__(256) void qkv_kernel(
    const float* __restrict__ x, const float* __restrict__ wq,
    const float* __restrict__ wk, const float* __restrict__ wv,
    const float* __restrict__ fcos, const float* __restrict__ fsin,
    float* __restrict__ q_ws, float* __restrict__ k_ws,
    float* __restrict__ v_ws) {
  __shared__ float red[4][16 * RPAD];
  const int tid = threadIdx.x;
  const int lane = tid & 63;
  const int wave = tid >> 6;
  const int row0 = blockIdx.x * 16 + wave * 4;

  const float* W;
  int rbase, kind;  // 0=q, 1=k, 2=v
  if (row0 < 4096)      { W = wq; rbase = row0;        kind = 0; }
  else if (row0 < 5120) { W = wk; rbase = row0 - 4096; kind = 1; }
  else                  { W = wv; rbase = row0 - 5120; kind = 2; }

  float res[4];
  gemv4_direct(x, W, rbase, red[wave], res, lane);

  if (kind <= 1) {  // RoPE on pairs (0,1) and (2,3); rbase % 4 == 0
#pragma unroll
    for (int pr = 0; pr < 2; ++pr) {
      int i = ((rbase + pr * 2) & 127) >> 1;
      float c = fcos[i], s = fsin[i];
      float a = res[pr * 2], b2 = res[pr * 2 + 1];
      res[pr * 2]     = a * c - b2 * s;
      res[pr * 2 + 1] = a * s + b2 * c;
    }
  }
  if ((lane & 3) == 0) {
    int b = lane >> 2;
    if (kind == 0) {
#pragma unroll
      for (int r = 0; r < 4; ++r) q_ws[(size_t)b * 4096 + rbase + r] = res[r];
    } else {
      int kvh = rbase >> 7, dpos = rbase & 127;
      float* dst = (kind == 1) ? k_ws : v_ws;
#pragma unroll
      for (int r = 0; r < 4; ++r)
        dst[((size_t)b * NKVH + kvh) * HD + dpos + r] = res[r];
    }
  }
}

// ---------------------------------------------------------------------------
// Kernel 2: flash-decode attention partials. Positions 0..4094 from the
// (unmodified) caches; position 4095 from k_ws/v_ws. grid (NSPLIT, NKVH, BSZ)
// = (32, 8, 16) = 4096 blocks; block 256. 4 GQA q-heads, 128 keys per block.
// ---------------------------------------------------------------------------
__global__ __launch_bounds__(256) void attn_kernel(
    const float* __restrict__ ck, const float* __restrict__ cv,
    const float* __restrict__ q_ws, const float* __restrict__ k_ws,
    const float* __restrict__ v_ws, float* __restrict__ ml_ws,
    float* __restrict__ opart) {
  __shared__ float sc[SPLITLEN * 4];   // [p][h]
  __shared__ float part[32 * 128];     // [half*16 + wave*4 + h][d]
  const int tid = threadIdx.x, lane = tid & 63, wave = tid >> 6;
  const int split = blockIdx.x, kvh = blockIdx.y, b = blockIdx.z;
  const int p0 = split * SPLITLEN;
  const float scale = 0.08838834764831845f;  // 1/sqrt(128)

  // ---- Phase 1: scores = q . k  (8 lanes per row, shuffle reduce) ----
  {
    const int dsub = (lane & 7) << 2;
    const int prow = lane >> 3;
    float4 q4[4][4];
#pragma unroll
    for (int h = 0; h < 4; ++h)
#pragma unroll
      for (int j = 0; j < 4; ++j) {
        float4 t = *(const float4*)(q_ws + (size_t)b * 4096 + (kvh * 4 + h) * 128 + j * 32 + dsub);
        q4[h][j] = make_float4(t.x * scale, t.y * scale, t.z * scale, t.w * scale);
      }
#pragma unroll 2
    for (int it = 0; it < SPLITLEN / 32; ++it) {
      int pl = wave * (SPLITLEN / 4) + it * 8 + prow;
      const float* kp = (p0 + pl == SEQ - 1)
                            ? (k_ws + ((size_t)b * NKVH + kvh) * HD)
                            : (ck + ((size_t)(b * 4096 + p0 + pl) * 8 + kvh) * 128);
      float s0 = 0, s1 = 0, s2 = 0, s3 = 0;
#pragma unroll
      for (int j = 0; j < 4; ++j) {
        v4f k4 = ldnt4(kp + j * 32 + dsub);
        s0 = fmaf(k4[0], q4[0][j].x, s0); s0 = fmaf(k4[1], q4[0][j].y, s0);
        s0 = fmaf(k4[2], q4[0][j].z, s0); s0 = fmaf(k4[3], q4[0][j].w, s0);
        s1 = fmaf(k4[0], q4[1][j].x, s1); s1 = fmaf(k4[1], q4[1][j].y, s1);
        s1 = fmaf(k4[2], q4[1][j].z, s1); s1 = fmaf(k4[3], q4[1][j].w, s1);
        s2 = fmaf(k4[0], q4[2][j].x, s2); s2 = fmaf(k4[1], q4[2][j].y, s2);
        s2 = fmaf(k4[2], q4[2][j].z, s2); s2 = fmaf(k4[3], q4[2][j].w, s2);
        s3 = fmaf(k4[0], q4[3][j].x, s3); s3 = fmaf(k4[1], q4[3][j].y, s3);
        s3 = fmaf(k4[2], q4[3][j].z, s3); s3 = fmaf(k4[3], q4[3][j].w, s3);
      }
#pragma unroll
      for (int m = 1; m <= 4; m <<= 1) {
        s0 += __shfl_xor(s0, m); s1 += __shfl_xor(s1, m);
        s2 += __shfl_xor(s2, m); s3 += __shfl_xor(s3, m);
      }
      if ((lane & 7) == 0)
        ((float4*)sc)[pl] = make_float4(s0, s1, s2, s3);
    }
  }
  __syncthreads();

  // ---- Phase 1.5: per-split softmax (wave w handles head w) ----
  {
    int h = wave;
    float vals[SPLITLEN / 64];
    float m = -1e30f;
#pragma unroll
    for (int k = 0; k < SPLITLEN / 64; ++k) {
      vals[k] = sc[(k * 64 + lane) * 4 + h];
      m = fmaxf(m, vals[k]);
    }
#pragma unroll
    for (int mk = 1; mk <= 32; mk <<= 1) m = fmaxf(m, __shfl_xor(m, mk));
    float lsum = 0;
#pragma unroll
    for (int k = 0; k < SPLITLEN / 64; ++k) {
      float e = __expf(vals[k] - m);
      sc[(k * 64 + lane) * 4 + h] = e;
      lsum += e;
    }
#pragma unroll
    for (int mk = 1; mk <= 32; mk <<= 1) lsum += __shfl_xor(lsum, mk);
    if (lane == 0) {
      int hg = kvh * 4 + h;
      ml_ws[((size_t)(b * 32 + hg) * NSPLIT + split) * 2 + 0] = m;
      ml_ws[((size_t)(b * 32 + hg) * NSPLIT + split) * 2 + 1] = lsum;
    }
  }
  __syncthreads();

  // ---- Phase 2: PV. 2 rows/iter (half-wave each), float4 loads ----
  {
    const int dq = lane & 31;     // float4 column index: d = dq*4
    const int half = lane >> 5;
    float4 a0 = {0,0,0,0}, a1 = {0,0,0,0}, a2 = {0,0,0,0}, a3 = {0,0,0,0};
#pragma unroll 4
    for (int it = 0; it < SPLITLEN / 8; ++it) {
      int pl = wave * (SPLITLEN / 4) + it * 2 + half;
      const float* vp = (p0 + pl == SEQ - 1)
                            ? (v_ws + ((size_t)b * NKVH + kvh) * HD)
                            : (cv + ((size_t)(b * 4096 + p0 + pl) * 8 + kvh) * 128);
      v4f v4 = ldnt4(vp + dq * 4);
      float4 s4 = ((const float4*)sc)[pl];  // 2-way LDS broadcast
      a0.x = fmaf(s4.x, v4[0], a0.x); a0.y = fmaf(s4.x, v4[1], a0.y);
      a0.z = fmaf(s4.x, v4[2], a0.z); a0.w = fmaf(s4.x, v4[3], a0.w);
      a1.x = fmaf(s4.y, v4[0], a1.x); a1.y = fmaf(s4.y, v4[1], a1.y);
      a1.z = fmaf(s4.y, v4[2], a1.z); a1.w = fmaf(s4.y, v4[3], a1.w);
      a2.x = fmaf(s4.z, v4[0], a2.x); a2.y = fmaf(s4.z, v4[1], a2.y);
      a2.z = fmaf(s4.z, v4[2], a2.z); a2.w = fmaf(s4.z, v4[3], a2.w);
      a3.x = fmaf(s4.w, v4[0], a3.x); a3.y = fmaf(s4.w, v4[1], a3.y);
      a3.z = fmaf(s4.w, v4[2], a3.z); a3.w = fmaf(s4.w, v4[3], a3.w);
    }
    int rb = (half * 16 + wave * 4) * 128 + dq * 4;
    *(float4*)&part[rb + 0 * 128] = a0;
    *(float4*)&part[rb + 1 * 128] = a1;
    *(float4*)&part[rb + 2 * 128] = a2;
    *(float4*)&part[rb + 3 * 128] = a3;
  }
  __syncthreads();
  {
    int hh = tid >> 6, dd = (tid & 63) * 2;
    float o0 = 0, o1 = 0;
#pragma unroll
    for (int g = 0; g < 8; ++g) {
      int row = (g >> 2) * 16 + (g & 3) * 4 + hh;
      float2 p2 = *(const float2*)&part[row * 128 + dd];
      o0 += p2.x; o1 += p2.y;
    }
    int hg = kvh * 4 + hh;
    size_t base = ((size_t)(b * 32 + hg) * NSPLIT + split) * 128;
    *(float2*)(opart + base + dd) = make_float2(o0, o1);
  }
}

// ---------------------------------------------------------------------------
// Kernel 3: combine split partials (flash rescale).
// ---------------------------------------------------------------------------
__global__ __launch_bounds__(128) void combine_kernel(
    const float* __restrict__ ml_ws, const float* __restrict__ opart,
    float* __restrict__ attn_ws) {
  int bh = blockIdx.x;  // b*32 + h
  int d = threadIdx.x;
  float mv[NSPLIT], lv[NSPLIT];
  float M = -1e30f;
#pragma unroll
  for (int i = 0; i < NSPLIT; ++i) {
    mv[i] = ml_ws[((size_t)bh * NSPLIT + i) * 2];
    lv[i] = ml_ws[((size_t)bh * NSPLIT + i) * 2 + 1];
    M = fmaxf(M, mv[i]);
  }
  float L = 0, o = 0;
#pragma unroll
  for (int i = 0; i < NSPLIT; ++i) {
    float w = __expf(mv[i] - M);
    L += w * lv[i];
    o += w * opart[((size_t)bh * NSPLIT + i) * 128 + d];
  }
  attn_ws[(size_t)bh * 128 + d] = o / L;
}

// ---------------------------------------------------------------------------
// Kernel 4: output projection with wo. 16 rows/block, grid 256 (1 block/CU).
// ---------------------------------------------------------------------------
__global__ __launch_bounds__(256) void oproj_kernel(
    const float* __restrict__ xin, const float* __restrict__ wo,
    float* __restrict__ out) {
  __shared__ float red[4][16 * RPAD];
  const int tid = threadIdx.x;
  const int lane = tid & 63;
  const int wave = tid >> 6;
  const int row0 = blockIdx.x * 16 + wave * 4;
  float res[4];
  gemv4_direct(xin, wo, row0, red[wave], res, lane);
  if ((lane & 3) == 0) {
    int b = lane >> 2;
#pragma unroll
    for (int r = 0; r < 4; ++r) out[(size_t)b * 4096 + row0 + r] = res[r];
  }
}

extern "C" void kernel_launch(void* const* d_in, const int* in_sizes, int n_in,
                              void* d_out, int out_size, void* d_ws, size_t ws_size,
                              hipStream_t stream) {
  const float* x  = (const float*)d_in[0];
  const float* wq = (const float*)d_in[1];
  const float* wk = (const float*)d_in[2];
  const float* wv = (const float*)d_in[3];
  const float* wo = (const float*)d_in[4];
  const float* ck = (const float*)d_in[5];  // NOT mutated
  const float* cv = (const float*)d_in[6];
  const float* fc = (const float*)d_in[7];
  const float* fs = (const float*)d_in[8];

  float* ws      = (float*)d_ws;
  float* q_ws    = ws;               // 16*4096            = 65536
  float* k_ws    = q_ws + 65536;     // 16*8*128           = 16384
  float* v_ws    = k_ws + 16384;     // 16*8*128           = 16384
  float* ml_ws   = v_ws + 16384;     // 16*32*32*2         = 32768
  float* opart   = ml_ws + 32768;    // 16*32*32*128       = 2097152
  float* attn_ws = opart + 2097152;  // 16*4096            = 65536
  // total ~9.2 MB of workspace

  qkv_kernel<<<384, 256, 0, stream>>>(x, wq, wk, wv, fc, fs, q_ws, k_ws, v_ws);
  attn_kernel<<<dim3(NSPLIT, NKVH, BSZ), 256, 0, stream>>>(ck, cv, q_ws, k_ws, v_ws,
                                                           ml_ws, opart);
  combine_kernel<<<BSZ * 32, 128, 0, stream>>>(ml_ws, opart, attn_ws);
  oproj_kernel<<<256, 256, 0, stream>>>(attn_ws, wo, (float*)d_out);
}